// Round 3
// baseline (389.758 us; speedup 1.0000x reference)
//
#include <hip/hip_runtime.h>

#define B_     16
#define N_IN_  6250
#define N_OUT_ 25000
#define C_     64
#define S_     9
#define NNZ_   75000
#define MT3_   49           // ceil(N_OUT/512)

typedef __bf16 bf16x8 __attribute__((ext_vector_type(8)));
typedef __bf16 bf16x2 __attribute__((ext_vector_type(2)));
typedef float floatx4 __attribute__((ext_vector_type(4)));

__device__ inline void async_copy16(const void* g, void* l) {
    __builtin_amdgcn_global_load_lds(
        (const __attribute__((address_space(1))) void*)g,
        (__attribute__((address_space(3))) void*)l, 16, 0, 0);
}

// ---------------- CSR build ----------------

__global__ void hist_kernel(const int* __restrict__ rows, int* __restrict__ counts, int nnz) {
    int i = blockIdx.x * blockDim.x + threadIdx.x;
    if (i < nnz) atomicAdd(&counts[rows[i]], 1);
}

// single-block scan over counts -> offsets (+cursor copy), replaces 3 kernels
__global__ __launch_bounds__(1024) void scan_kernel(
        const int* __restrict__ counts, int* __restrict__ offsets,
        int* __restrict__ cursor, int n) {
    __shared__ int wsum[16];
    __shared__ int carry;
    int t = threadIdx.x;
    int wid = t >> 6, lane = t & 63;
    if (t == 0) carry = 0;
    __syncthreads();
    for (int base = 0; base < n; base += 1024) {
        int i = base + t;
        int v = (i < n) ? counts[i] : 0;
        int s = v;
        #pragma unroll
        for (int d = 1; d < 64; d <<= 1) {
            int u = __shfl_up(s, d, 64);
            if (lane >= d) s += u;
        }
        if (lane == 63) wsum[wid] = s;
        __syncthreads();
        if (wid == 0 && lane < 16) {
            int ws = wsum[lane];
            #pragma unroll
            for (int d = 1; d < 16; d <<= 1) {
                int u = __shfl_up(ws, d, 64);
                if (lane >= d) ws += u;
            }
            wsum[lane] = ws;
        }
        __syncthreads();
        int wave_off = (wid == 0) ? 0 : wsum[wid - 1];
        int incl = s + wave_off + carry;
        if (i < n) {
            int o = incl - v;
            offsets[i] = o;
            cursor[i] = o;
        }
        __syncthreads();                 // all carry reads done
        if (t == 1023) carry = incl;
        __syncthreads();
    }
    if (t == 0) offsets[n] = carry;
}

__global__ void fill_kernel(const int* __restrict__ rows, const int* __restrict__ cols,
                            const float* __restrict__ vals, int* __restrict__ cursor,
                            int* __restrict__ ecol, float* __restrict__ eval, int nnz) {
    int i = blockIdx.x * blockDim.x + threadIdx.x;
    if (i < nnz) {
        int p = atomicAdd(&cursor[rows[i]], 1);
        ecol[p] = cols[i];
        eval[p] = vals[i];
    }
}

// ---------------- pooling (CSR gather), XCD-affine batch pairs ----------------
// grid: 8 * 3125 blocks; bx&7 = xcd -> batches {xcd, xcd+8} only, so each
// XCD's x working set is 2 x 1.6MB = 3.2MB -> L2-resident (was 25.6MB/L3).
// Block = 4 waves; wave handles 2 rows (independent chains). Lane = (batch
// half b2 = lane>>5, float2 channels c2 = (lane&31)*2).
__global__ __launch_bounds__(256) void pool_kernel(
        const float* __restrict__ x, const int* __restrict__ offsets,
        const int* __restrict__ ecol, const float* __restrict__ eval,
        __bf16* __restrict__ pooled) {
    int bx = blockIdx.x;
    int xcd = bx & 7;
    int rg = bx >> 3;                    // 0..3124 -> rows rg*8 .. rg*8+7
    int t = threadIdx.x;
    int wid = t >> 6, lane = t & 63;
    int b = xcd + 8 * (lane >> 5);
    int c2 = (lane & 31) * 2;
    const float* xb = x + (size_t)b * N_IN_ * C_ + c2;

    #pragma unroll
    for (int r = 0; r < 2; ++r) {
        int row = rg * 8 + wid * 2 + r;
        int beg = offsets[row], end = offsets[row + 1];
        float ax = 0.f, ay = 0.f;
        int col = 0; float v = 0.f;
        if (beg < end) { col = ecol[beg]; v = eval[beg]; }
        for (int k = beg; k < end; ++k) {
            int col2 = 0; float v2 = 0.f;
            if (k + 1 < end) { col2 = ecol[k + 1]; v2 = eval[k + 1]; }
            const float2 xv = *reinterpret_cast<const float2*>(xb + (size_t)col * C_);
            ax += xv.x * v;
            ay += xv.y * v;
            col = col2; v = v2;
        }
        bf16x2 o;
        o[0] = (__bf16)ax; o[1] = (__bf16)ay;
        *reinterpret_cast<bf16x2*>(pooled + ((size_t)b * N_OUT_ + row) * C_ + c2) = o;
    }
}

// ---------------- W -> WtF (bf16, MFMA-fragment-major) ----------------
// WtF[(kb*64 + n)*8 + j] = W[(kb*8 + j)*64 + n], kb = k/8 in [0,72).
__global__ void convw_kernel(const float* __restrict__ W, __bf16* __restrict__ WtF) {
    int i = blockIdx.x * blockDim.x + threadIdx.x;   // over 72*64*8
    if (i < 72 * 64 * 8) {
        int kb = i >> 9;
        int n  = (i >> 3) & 63;
        int j  = i & 7;
        WtF[i] = (__bf16)W[(kb * 8 + j) * 64 + n];
    }
}

// ---------------- spiral gather + GEMM + bias + ELU ----------------
// grid 1D = 8 * (2*MT3_) = 784, XCD-affine: bx&7 = xcd, one batch per block.
// Block = 8 waves x 64 rows = 512 rows; 2 blocks/CU (73.7KB LDS) -> 16
// waves/CU for latency hiding (was 8). Per wave: 4 mi x 4 nt x K=576 ->
// 288 MFMAs, B fragments from LDS (fragment-major, conflict-free), A
// register double-buffered with 1-deep prefetch.
__global__ __launch_bounds__(512, 4) void gemm_kernel(
        const __bf16* __restrict__ pooled, const int* __restrict__ spiral,
        const __bf16* __restrict__ WtF, const float* __restrict__ bias,
        float* __restrict__ out) {
    __shared__ __bf16 Bs[72 * 64 * 8];   // 73728 B -> 2 blocks/CU

    int bx = blockIdx.x;
    int xcd = bx & 7;
    int rr = bx >> 3;                    // 0..2*MT3_-1
    int half = (rr >= MT3_) ? 1 : 0;
    int mt = rr - half * MT3_;           // 0..48
    int b = xcd + 8 * half;

    int t = threadIdx.x;
    int wave = t >> 6, lane = t & 63;
    int quad = lane >> 4, l16 = lane & 15;
    int mbase = mt * 512 + wave * 64;

    // stage WtF -> Bs, lane-linear 16B chunks (4608 total, 9/thread)
    #pragma unroll
    for (int j = 0; j < 9; ++j) {
        int idx = t + j * 512;
        async_copy16((const char*)WtF + (size_t)idx * 16, (char*)Bs + idx * 16);
    }

    // per-lane spiral indices for the 4 m-subtiles, vectorized 4+4+1
    int src[4][S_];
    #pragma unroll
    for (int mi = 0; mi < 4; ++mi) {
        int m = mbase + mi * 16 + l16;
        int mc = (m < N_OUT_) ? m : 0;
        const int* sp = spiral + (size_t)mc * S_;
        int4 a0 = *reinterpret_cast<const int4*>(sp);
        int4 a1 = *reinterpret_cast<const int4*>(sp + 4);
        src[mi][0] = a0.x; src[mi][1] = a0.y; src[mi][2] = a0.z; src[mi][3] = a0.w;
        src[mi][4] = a1.x; src[mi][5] = a1.y; src[mi][6] = a1.z; src[mi][7] = a1.w;
        src[mi][8] = sp[8];
    }
    const __bf16* poolb = pooled + (size_t)b * N_OUT_ * C_;

    __syncthreads();   // staging drained (single barrier of the kernel)

    floatx4 acc[4][4] = {};
    bf16x8 Acur[4][2], Anxt[4][2];

    auto loadA = [&](int s, bf16x8 (*A)[2]) {
        #pragma unroll
        for (int mi = 0; mi < 4; ++mi) {
            const __bf16* p = poolb + (size_t)src[mi][s] * C_ + quad * 8;
            A[mi][0] = *reinterpret_cast<const bf16x8*>(p);
            A[mi][1] = *reinterpret_cast<const bf16x8*>(p + 32);
        }
    };

    loadA(0, Acur);
    #pragma unroll
    for (int s = 0; s < S_; ++s) {
        if (s + 1 < S_) {
            loadA(s + 1, (s & 1) ? Acur : Anxt);   // prefetch next step
            __builtin_amdgcn_sched_barrier(0);     // pin: loads stay ahead of MFMAs
        }
        bf16x8 (*A)[2] = (s & 1) ? Anxt : Acur;
        #pragma unroll
        for (int kc = 0; kc < 2; ++kc) {
            #pragma unroll
            for (int nt = 0; nt < 4; ++nt) {
                int kb = s * 8 + kc * 4 + quad;
                bf16x8 bb = *reinterpret_cast<const bf16x8*>(
                    Bs + (((kb << 6) + (nt << 4) + l16) << 3));
                #pragma unroll
                for (int mi = 0; mi < 4; ++mi)
                    acc[mi][nt] = __builtin_amdgcn_mfma_f32_16x16x32_bf16(
                        A[mi][kc], bb, acc[mi][nt], 0, 0, 0);
            }
        }
    }

    // epilogue: D[m = quad*4 + i][n = l16] per (mi, nt) tile
    float* outb = out + (size_t)b * N_OUT_ * C_;
    #pragma unroll
    for (int mi = 0; mi < 4; ++mi) {
        #pragma unroll
        for (int nt = 0; nt < 4; ++nt) {
            float bn = bias[nt * 16 + l16];
            #pragma unroll
            for (int i = 0; i < 4; ++i) {
                int mm = mbase + mi * 16 + quad * 4 + i;
                if (mm < N_OUT_) {
                    float v = acc[mi][nt][i] + bn;
                    v = (v > 0.0f) ? v : expm1f(v);
                    outb[(size_t)mm * C_ + nt * 16 + l16] = v;
                }
            }
        }
    }
}

extern "C" void kernel_launch(void* const* d_in, const int* in_sizes, int n_in,
                              void* d_out, int out_size, void* d_ws, size_t ws_size,
                              hipStream_t stream) {
    const float* x      = (const float*)d_in[0];
    const float* tvals  = (const float*)d_in[1];
    const int*   trow   = (const int*)d_in[2];
    const int*   tcol   = (const int*)d_in[3];
    const int*   spiral = (const int*)d_in[4];
    const float* W      = (const float*)d_in[5];
    const float* bias   = (const float*)d_in[6];
    float* out = (float*)d_out;

    char* ws = (char*)d_ws;
    size_t off = 0;
    auto alloc = [&](size_t bytes) -> void* {
        void* p = ws + off;
        off += (bytes + 255) & ~(size_t)255;
        return p;
    };
    __bf16* pooled  = (__bf16*)alloc((size_t)B_ * N_OUT_ * C_ * 2);   // 51.2 MB
    __bf16* WtF     = (__bf16*)alloc(72 * 64 * 8 * 2);
    int*    cursor  = (int*)alloc(N_OUT_ * 4);
    int*    offsets = (int*)alloc((N_OUT_ + 1) * 4);
    int*    ecol    = (int*)alloc(NNZ_ * 4);
    float*  eval    = (float*)alloc(NNZ_ * 4);
    int*    counts  = (int*)alloc(N_OUT_ * 4);

    hipMemsetAsync(counts, 0, N_OUT_ * 4, stream);
    hist_kernel<<<(NNZ_ + 255) / 256, 256, 0, stream>>>(trow, counts, NNZ_);
    scan_kernel<<<1, 1024, 0, stream>>>(counts, offsets, cursor, N_OUT_);
    fill_kernel<<<(NNZ_ + 255) / 256, 256, 0, stream>>>(trow, tcol, tvals, cursor, ecol, eval, NNZ_);
    convw_kernel<<<(72 * 64 * 8 + 255) / 256, 256, 0, stream>>>(W, WtF);
    pool_kernel<<<8 * (N_OUT_ / 8), 256, 0, stream>>>(x, offsets, ecol, eval, pooled);
    gemm_kernel<<<8 * (2 * MT3_), 512, 0, stream>>>(pooled, spiral, WtF, bias, out);
}

// Round 4
// 319.706 us; speedup vs baseline: 1.2191x; 1.2191x over previous
//
#include <hip/hip_runtime.h>

#define B_     16
#define N_IN_  6250
#define N_OUT_ 25000
#define C_     64
#define S_     9
#define NNZ_   75000
#define MT2_   98           // ceil(N_OUT/256)

typedef __bf16 bf16x8 __attribute__((ext_vector_type(8)));
typedef float floatx4 __attribute__((ext_vector_type(4)));

__device__ inline void async_copy16(const void* g, void* l) {
    __builtin_amdgcn_global_load_lds(
        (const __attribute__((address_space(1))) void*)g,
        (__attribute__((address_space(3))) void*)l, 16, 0, 0);
}

// ---------------- CSR build ----------------

__global__ void hist_kernel(const int* __restrict__ rows, int* __restrict__ counts, int nnz) {
    int i = blockIdx.x * blockDim.x + threadIdx.x;
    if (i < nnz) atomicAdd(&counts[rows[i]], 1);
}

__global__ void scan1_kernel(const int* __restrict__ counts, int* __restrict__ offsets,
                             int* __restrict__ bsum, int n) {
    __shared__ int wsum[16];
    int t = threadIdx.x;
    int wid = t >> 6, lane = t & 63;
    int i = blockIdx.x * 1024 + t;
    int v = (i < n) ? counts[i] : 0;
    int s = v;
    #pragma unroll
    for (int d = 1; d < 64; d <<= 1) {
        int u = __shfl_up(s, d, 64);
        if (lane >= d) s += u;
    }
    if (lane == 63) wsum[wid] = s;
    __syncthreads();
    if (wid == 0 && lane < 16) {
        int ws = wsum[lane];
        #pragma unroll
        for (int d = 1; d < 16; d <<= 1) {
            int u = __shfl_up(ws, d, 64);
            if (lane >= d) ws += u;
        }
        wsum[lane] = ws;
    }
    __syncthreads();
    int wave_off = (wid == 0) ? 0 : wsum[wid - 1];
    int incl = s + wave_off;
    if (i < n) offsets[i] = incl - v;
    if (t == 1023) bsum[blockIdx.x] = incl;
}

__global__ void scan2_kernel(int* __restrict__ bsum, int* __restrict__ offsets, int nblk, int n) {
    if (threadIdx.x == 0) {
        int t = 0;
        for (int i = 0; i < nblk; ++i) { int v = bsum[i]; bsum[i] = t; t += v; }
        offsets[n] = t;
    }
}

__global__ void scan3_kernel(int* __restrict__ offsets, const int* __restrict__ bsum,
                             int* __restrict__ cursor, int n) {
    int i = blockIdx.x * 1024 + threadIdx.x;
    if (i < n) {
        int o = offsets[i] + bsum[blockIdx.x];
        offsets[i] = o;
        cursor[i] = o;
    }
}

__global__ void fill_kernel(const int* __restrict__ rows, const int* __restrict__ cols,
                            const float* __restrict__ vals, int* __restrict__ cursor,
                            int* __restrict__ ecol, float* __restrict__ eval, int nnz) {
    int i = blockIdx.x * blockDim.x + threadIdx.x;
    if (i < nnz) {
        int p = atomicAdd(&cursor[rows[i]], 1);
        ecol[p] = cols[i];
        eval[p] = vals[i];
    }
}

// ---------------- pooling (CSR gather), wave-per-row ----------------
// grid: N_OUT/4 blocks x 256 threads = 4 waves; wave w owns row blockIdx*4+w.
// Lane = (batch b = lane>>2, channel quad cq = (lane&3)*16). 16 f32 acc/lane.
// No LDS, no barriers; ecol/eval broadcast-loaded with 1-ahead prefetch.
__global__ __launch_bounds__(256) void pool_kernel(
        const float* __restrict__ x, const int* __restrict__ offsets,
        const int* __restrict__ ecol, const float* __restrict__ eval,
        __bf16* __restrict__ pooled) {
    int t = threadIdx.x;
    int wid = t >> 6, lane = t & 63;
    int row = blockIdx.x * 4 + wid;
    int b = lane >> 2;
    int cq = (lane & 3) << 4;
    int beg = offsets[row], end = offsets[row + 1];

    const float* xb = x + (size_t)b * N_IN_ * C_ + cq;
    floatx4 acc[4] = {};

    int col = 0; float v = 0.f;
    if (beg < end) { col = ecol[beg]; v = eval[beg]; }
    for (int k = beg; k < end; ++k) {
        int col2 = 0; float v2 = 0.f;
        if (k + 1 < end) { col2 = ecol[k + 1]; v2 = eval[k + 1]; }
        const floatx4* xp = reinterpret_cast<const floatx4*>(xb + (size_t)col * C_);
        #pragma unroll
        for (int j = 0; j < 4; ++j) acc[j] += xp[j] * v;
        col = col2; v = v2;
    }

    __bf16* op = pooled + ((size_t)b * N_OUT_ + row) * C_ + cq;
    bf16x8 o0, o1;
    #pragma unroll
    for (int j = 0; j < 4; ++j) {
        o0[j]     = (__bf16)acc[0][j];
        o0[j + 4] = (__bf16)acc[1][j];
        o1[j]     = (__bf16)acc[2][j];
        o1[j + 4] = (__bf16)acc[3][j];
    }
    *reinterpret_cast<bf16x8*>(op)     = o0;
    *reinterpret_cast<bf16x8*>(op + 8) = o1;
}

// ---------------- W -> WtF (bf16, MFMA-fragment-major) ----------------
// WtF[(kb*64 + n)*8 + j] = W[(kb*8 + j)*64 + n], kb = k/8 in [0,72).
__global__ void convw_kernel(const float* __restrict__ W, __bf16* __restrict__ WtF) {
    int i = blockIdx.x * blockDim.x + threadIdx.x;   // over 72*64*8
    if (i < 72 * 64 * 8) {
        int kb = i >> 9;
        int n  = (i >> 3) & 63;
        int j  = i & 7;
        WtF[i] = (__bf16)W[(kb * 8 + j) * 64 + n];
    }
}

// ---------------- spiral gather + GEMM + bias + ELU ----------------
// grid 1D = 8 * 392 = 3136, XCD-affine: bx&7 = xcd. rr = bx>>3 in [0,392):
// half = rr>=196 selects batch b = xcd + 8*half; rr2 = rr%196: mt = rr2>>1
// (256-row tile), nh = rr2&1 (32-col half of N=64). Sibling nh blocks are
// adjacent in dispatch order -> read identical A rows (L2 hit).
// N-split halves LDS to 36864 B -> 4 blocks/CU = 16 waves/CU (2x round-2
// occupancy) with LOWER register pressure (acc 64->32 VGPRs). Per wave:
// 4 mi x 2 nt x K=576 -> 144 MFMAs; B fragment-major in LDS, conflict-free;
// A register double-buffered with 1-deep prefetch.
__global__ __launch_bounds__(256, 2) void gemm_kernel(
        const __bf16* __restrict__ pooled, const int* __restrict__ spiral,
        const __bf16* __restrict__ WtF, const float* __restrict__ bias,
        float* __restrict__ out) {
    __shared__ __bf16 Bs[72 * 32 * 8];   // 36864 B -> 4 blocks/CU

    int bx = blockIdx.x;
    int xcd = bx & 7;
    int rr = bx >> 3;                    // 0..391
    int half = (rr >= 196) ? 1 : 0;
    int rr2 = rr - half * 196;           // 0..195
    int mt = rr2 >> 1;                   // 0..97
    int nh = rr2 & 1;                    // which 32-col half
    int b = xcd + 8 * half;

    int t = threadIdx.x;
    int wave = t >> 6, lane = t & 63;
    int quad = lane >> 4, l16 = lane & 15;
    int mbase = mt * 256 + wave * 64;

    // stage this half's WtF columns -> Bs, lane-linear 16B chunks.
    // local chunk jl = kb*32 + rem (rem in [0,32)) <- global chunk kb*64 + nh*32 + rem
    #pragma unroll
    for (int j = 0; j < 9; ++j) {
        int jl = t + j * 256;
        int kb = jl >> 5;
        int rem = jl & 31;
        async_copy16((const char*)WtF + (size_t)((kb << 6) + (nh << 5) + rem) * 16,
                     (char*)Bs + (size_t)jl * 16);
    }

    // per-lane spiral indices for the 4 m-subtiles, vectorized 4+4+1
    int src[4][S_];
    #pragma unroll
    for (int mi = 0; mi < 4; ++mi) {
        int m = mbase + mi * 16 + l16;
        int mc = (m < N_OUT_) ? m : 0;
        const int* sp = spiral + (size_t)mc * S_;
        int4 a0 = *reinterpret_cast<const int4*>(sp);
        int4 a1 = *reinterpret_cast<const int4*>(sp + 4);
        src[mi][0] = a0.x; src[mi][1] = a0.y; src[mi][2] = a0.z; src[mi][3] = a0.w;
        src[mi][4] = a1.x; src[mi][5] = a1.y; src[mi][6] = a1.z; src[mi][7] = a1.w;
        src[mi][8] = sp[8];
    }
    const __bf16* poolb = pooled + (size_t)b * N_OUT_ * C_;

    __syncthreads();   // staging drained (single barrier of the kernel)

    floatx4 acc[4][2] = {};
    bf16x8 Acur[4][2], Anxt[4][2];

    auto loadA = [&](int s, bf16x8 (*A)[2]) {
        #pragma unroll
        for (int mi = 0; mi < 4; ++mi) {
            const __bf16* p = poolb + (size_t)src[mi][s] * C_ + quad * 8;
            A[mi][0] = *reinterpret_cast<const bf16x8*>(p);
            A[mi][1] = *reinterpret_cast<const bf16x8*>(p + 32);
        }
    };

    loadA(0, Acur);
    #pragma unroll
    for (int s = 0; s < S_; ++s) {
        if (s + 1 < S_) {
            loadA(s + 1, (s & 1) ? Acur : Anxt);   // prefetch next step
            __builtin_amdgcn_sched_barrier(0);     // pin: loads stay ahead of MFMAs
        }
        bf16x8 (*A)[2] = (s & 1) ? Anxt : Acur;
        #pragma unroll
        for (int kc = 0; kc < 2; ++kc) {
            #pragma unroll
            for (int nt = 0; nt < 2; ++nt) {
                int kb = s * 8 + kc * 4 + quad;
                bf16x8 bb = *reinterpret_cast<const bf16x8*>(
                    Bs + (((kb << 5) + (nt << 4) + l16) << 3));
                #pragma unroll
                for (int mi = 0; mi < 4; ++mi)
                    acc[mi][nt] = __builtin_amdgcn_mfma_f32_16x16x32_bf16(
                        A[mi][kc], bb, acc[mi][nt], 0, 0, 0);
            }
        }
    }

    // epilogue: D[m = quad*4 + i][n = nh*32 + nt*16 + l16] per (mi, nt) tile
    float* outb = out + (size_t)b * N_OUT_ * C_;
    #pragma unroll
    for (int mi = 0; mi < 4; ++mi) {
        #pragma unroll
        for (int nt = 0; nt < 2; ++nt) {
            int col = (nh << 5) + (nt << 4) + l16;
            float bn = bias[col];
            #pragma unroll
            for (int i = 0; i < 4; ++i) {
                int mm = mbase + mi * 16 + quad * 4 + i;
                if (mm < N_OUT_) {
                    float v = acc[mi][nt][i] + bn;
                    v = (v > 0.0f) ? v : expm1f(v);
                    outb[(size_t)mm * C_ + col] = v;
                }
            }
        }
    }
}

extern "C" void kernel_launch(void* const* d_in, const int* in_sizes, int n_in,
                              void* d_out, int out_size, void* d_ws, size_t ws_size,
                              hipStream_t stream) {
    const float* x      = (const float*)d_in[0];
    const float* tvals  = (const float*)d_in[1];
    const int*   trow   = (const int*)d_in[2];
    const int*   tcol   = (const int*)d_in[3];
    const int*   spiral = (const int*)d_in[4];
    const float* W      = (const float*)d_in[5];
    const float* bias   = (const float*)d_in[6];
    float* out = (float*)d_out;

    char* ws = (char*)d_ws;
    size_t off = 0;
    auto alloc = [&](size_t bytes) -> void* {
        void* p = ws + off;
        off += (bytes + 255) & ~(size_t)255;
        return p;
    };
    __bf16* pooled  = (__bf16*)alloc((size_t)B_ * N_OUT_ * C_ * 2);   // 51.2 MB
    __bf16* WtF     = (__bf16*)alloc(72 * 64 * 8 * 2);
    int*    cursor  = (int*)alloc(N_OUT_ * 4);
    int*    offsets = (int*)alloc((N_OUT_ + 1) * 4);
    int*    ecol    = (int*)alloc(NNZ_ * 4);
    float*  eval    = (float*)alloc(NNZ_ * 4);
    int*    counts  = (int*)alloc(N_OUT_ * 4);
    int*    bsum    = (int*)alloc(32 * 4);

    const int NBLK = (N_OUT_ + 1023) / 1024;   // 25
    hipMemsetAsync(counts, 0, N_OUT_ * 4, stream);
    hist_kernel<<<(NNZ_ + 255) / 256, 256, 0, stream>>>(trow, counts, NNZ_);
    scan1_kernel<<<NBLK, 1024, 0, stream>>>(counts, offsets, bsum, N_OUT_);
    scan2_kernel<<<1, 64, 0, stream>>>(bsum, offsets, NBLK, N_OUT_);
    scan3_kernel<<<NBLK, 1024, 0, stream>>>(offsets, bsum, cursor, N_OUT_);
    fill_kernel<<<(NNZ_ + 255) / 256, 256, 0, stream>>>(trow, tcol, tvals, cursor, ecol, eval, NNZ_);
    pool_kernel<<<N_OUT_ / 4, 256, 0, stream>>>(x, offsets, ecol, eval, pooled);
    convw_kernel<<<(72 * 64 * 8 + 255) / 256, 256, 0, stream>>>(W, WtF);
    gemm_kernel<<<8 * (2 * 196), 256, 0, stream>>>(pooled, spiral, WtF, bias, out);
}

// Round 5
// 311.430 us; speedup vs baseline: 1.2515x; 1.0266x over previous
//
#include <hip/hip_runtime.h>

#define B_     16
#define N_IN_  6250
#define N_OUT_ 25000
#define C_     64
#define S_     9
#define NNZ_   75000
#define MT2_   98           // ceil(N_OUT/256)

typedef __bf16 bf16x8 __attribute__((ext_vector_type(8)));
typedef __bf16 bf16x2 __attribute__((ext_vector_type(2)));
typedef float floatx4 __attribute__((ext_vector_type(4)));

__device__ inline void async_copy16(const void* g, void* l) {
    __builtin_amdgcn_global_load_lds(
        (const __attribute__((address_space(1))) void*)g,
        (__attribute__((address_space(3))) void*)l, 16, 0, 0);
}

// ---------------- CSR build ----------------

__global__ void hist_kernel(const int* __restrict__ rows, int* __restrict__ counts, int nnz) {
    int i = blockIdx.x * blockDim.x + threadIdx.x;
    if (i < nnz) atomicAdd(&counts[rows[i]], 1);
}

__global__ void scan1_kernel(const int* __restrict__ counts, int* __restrict__ offsets,
                             int* __restrict__ bsum, int n) {
    __shared__ int wsum[16];
    int t = threadIdx.x;
    int wid = t >> 6, lane = t & 63;
    int i = blockIdx.x * 1024 + t;
    int v = (i < n) ? counts[i] : 0;
    int s = v;
    #pragma unroll
    for (int d = 1; d < 64; d <<= 1) {
        int u = __shfl_up(s, d, 64);
        if (lane >= d) s += u;
    }
    if (lane == 63) wsum[wid] = s;
    __syncthreads();
    if (wid == 0 && lane < 16) {
        int ws = wsum[lane];
        #pragma unroll
        for (int d = 1; d < 16; d <<= 1) {
            int u = __shfl_up(ws, d, 64);
            if (lane >= d) ws += u;
        }
        wsum[lane] = ws;
    }
    __syncthreads();
    int wave_off = (wid == 0) ? 0 : wsum[wid - 1];
    int incl = s + wave_off;
    if (i < n) offsets[i] = incl - v;
    if (t == 1023) bsum[blockIdx.x] = incl;
}

__global__ void scan2_kernel(int* __restrict__ bsum, int* __restrict__ offsets, int nblk, int n) {
    if (threadIdx.x == 0) {
        int t = 0;
        for (int i = 0; i < nblk; ++i) { int v = bsum[i]; bsum[i] = t; t += v; }
        offsets[n] = t;
    }
}

__global__ void scan3_kernel(int* __restrict__ offsets, const int* __restrict__ bsum,
                             int* __restrict__ cursor, int n) {
    int i = blockIdx.x * 1024 + threadIdx.x;
    if (i < n) {
        int o = offsets[i] + bsum[blockIdx.x];
        offsets[i] = o;
        cursor[i] = o;
    }
}

__global__ void fill_kernel(const int* __restrict__ rows, const int* __restrict__ cols,
                            const float* __restrict__ vals, int* __restrict__ cursor,
                            int* __restrict__ ecol, float* __restrict__ eval, int nnz) {
    int i = blockIdx.x * blockDim.x + threadIdx.x;
    if (i < nnz) {
        int p = atomicAdd(&cursor[rows[i]], 1);
        ecol[p] = cols[i];
        eval[p] = vals[i];
    }
}

// ---------------- pooling (CSR gather), XCD-affine batch pairs ----------------
// grid: 8 * 3125 blocks; bx&7 = xcd -> batches {xcd, xcd+8} only, so each
// XCD's x working set is 2 x 1.6MB = 3.2MB -> L2-resident (was 25.6MB -> L3).
// Block = 4 waves; wave handles 2 rows (independent chains). Lane = (batch
// half bh = lane>>5, float2 channels c2 = (lane&31)*2).
__global__ __launch_bounds__(256) void pool_kernel(
        const float* __restrict__ x, const int* __restrict__ offsets,
        const int* __restrict__ ecol, const float* __restrict__ eval,
        __bf16* __restrict__ pooled) {
    int bx = blockIdx.x;
    int xcd = bx & 7;
    int rg = bx >> 3;                    // 0..3124 -> rows rg*8 .. rg*8+7
    int t = threadIdx.x;
    int wid = t >> 6, lane = t & 63;
    int b = xcd + 8 * (lane >> 5);
    int c2 = (lane & 31) * 2;
    const float* xb = x + (size_t)b * N_IN_ * C_ + c2;

    #pragma unroll
    for (int r = 0; r < 2; ++r) {
        int row = rg * 8 + wid * 2 + r;
        int beg = offsets[row], end = offsets[row + 1];
        float ax = 0.f, ay = 0.f;
        int col = 0; float v = 0.f;
        if (beg < end) { col = ecol[beg]; v = eval[beg]; }
        for (int k = beg; k < end; ++k) {
            int col2 = 0; float v2 = 0.f;
            if (k + 1 < end) { col2 = ecol[k + 1]; v2 = eval[k + 1]; }
            const float2 xv = *reinterpret_cast<const float2*>(xb + (size_t)col * C_);
            ax += xv.x * v;
            ay += xv.y * v;
            col = col2; v = v2;
        }
        bf16x2 o;
        o[0] = (__bf16)ax; o[1] = (__bf16)ay;
        *reinterpret_cast<bf16x2*>(pooled + ((size_t)b * N_OUT_ + row) * C_ + c2) = o;
    }
}

// ---------------- W -> WtF (bf16, MFMA-fragment-major) ----------------
// WtF[(kb*64 + n)*8 + j] = W[(kb*8 + j)*64 + n], kb = k/8 in [0,72).
__global__ void convw_kernel(const float* __restrict__ W, __bf16* __restrict__ WtF) {
    int i = blockIdx.x * blockDim.x + threadIdx.x;   // over 72*64*8
    if (i < 72 * 64 * 8) {
        int kb = i >> 9;
        int n  = (i >> 3) & 63;
        int j  = i & 7;
        WtF[i] = (__bf16)W[(kb * 8 + j) * 64 + n];
    }
}

// ---------------- spiral gather + GEMM + bias + ELU ----------------
// grid 1D = 8 * (2*MT2_), XCD-affine: bx&7 = xcd, one batch per block;
// first dispatch half = batches 0-7 (one per XCD) -> per-XCD pooled working
// set 3.2MB, L2-resident. Block = 4 waves x 64 rows = 256 rows; LDS 73.7KB
// -> 2 blocks/CU. Per wave: 4 mi x 4 nt x K=576 -> 288 MFMAs; B fragment-
// major in LDS (conflict-free); A register-prefetched DEPTH 2 (A0/A1/A2,
// compile-time rotation) so each step's gathers get ~2 steps of MFMA cover.
__global__ __launch_bounds__(256, 2) void gemm_kernel(
        const __bf16* __restrict__ pooled, const int* __restrict__ spiral,
        const __bf16* __restrict__ WtF, const float* __restrict__ bias,
        float* __restrict__ out) {
    __shared__ __bf16 Bs[72 * 64 * 8];   // 73728 B -> 2 blocks/CU

    int bx = blockIdx.x;
    int xcd = bx & 7;
    int rr = bx >> 3;                    // 0..2*MT2_-1
    int half = (rr >= MT2_) ? 1 : 0;
    int mt = rr - half * MT2_;           // 0..97
    int b = xcd + 8 * half;

    int t = threadIdx.x;
    int wave = t >> 6, lane = t & 63;
    int quad = lane >> 4, l16 = lane & 15;
    int mbase = mt * 256 + wave * 64;

    // stage WtF -> Bs, lane-linear 16B chunks (4608 total, 18/thread)
    #pragma unroll
    for (int j = 0; j < 18; ++j) {
        int idx = t + j * 256;
        async_copy16((const char*)WtF + (size_t)idx * 16, (char*)Bs + idx * 16);
    }

    // per-lane spiral indices for the 4 m-subtiles, vectorized 4+4+1
    int src[4][S_];
    #pragma unroll
    for (int mi = 0; mi < 4; ++mi) {
        int m = mbase + mi * 16 + l16;
        int mc = (m < N_OUT_) ? m : 0;
        const int* sp = spiral + (size_t)mc * S_;
        int4 a0 = *reinterpret_cast<const int4*>(sp);
        int4 a1 = *reinterpret_cast<const int4*>(sp + 4);
        src[mi][0] = a0.x; src[mi][1] = a0.y; src[mi][2] = a0.z; src[mi][3] = a0.w;
        src[mi][4] = a1.x; src[mi][5] = a1.y; src[mi][6] = a1.z; src[mi][7] = a1.w;
        src[mi][8] = sp[8];
    }
    const __bf16* poolb = pooled + (size_t)b * N_OUT_ * C_;

    __syncthreads();   // staging drained (single barrier of the kernel)

    floatx4 acc[4][4] = {};
    bf16x8 A0[4][2], A1[4][2], A2[4][2];

    auto loadA = [&](int s, bf16x8 (*A)[2]) {
        #pragma unroll
        for (int mi = 0; mi < 4; ++mi) {
            const __bf16* p = poolb + (size_t)src[mi][s] * C_ + quad * 8;
            A[mi][0] = *reinterpret_cast<const bf16x8*>(p);
            A[mi][1] = *reinterpret_cast<const bf16x8*>(p + 32);
        }
    };

    loadA(0, A0);
    loadA(1, A1);
    #pragma unroll
    for (int s = 0; s < S_; ++s) {
        if (s + 2 < S_) {
            // depth-2 prefetch into the buffer consumed at step s+2
            bf16x8 (*Apf)[2] = ((s + 2) % 3 == 0) ? A0 : (((s + 2) % 3 == 1) ? A1 : A2);
            loadA(s + 2, Apf);
            __builtin_amdgcn_sched_barrier(0);     // pin: loads stay ahead of MFMAs
        }
        bf16x8 (*A)[2] = (s % 3 == 0) ? A0 : ((s % 3 == 1) ? A1 : A2);
        #pragma unroll
        for (int kc = 0; kc < 2; ++kc) {
            #pragma unroll
            for (int nt = 0; nt < 4; ++nt) {
                int kb = s * 8 + kc * 4 + quad;
                bf16x8 bb = *reinterpret_cast<const bf16x8*>(
                    Bs + (((kb << 6) + (nt << 4) + l16) << 3));
                #pragma unroll
                for (int mi = 0; mi < 4; ++mi)
                    acc[mi][nt] = __builtin_amdgcn_mfma_f32_16x16x32_bf16(
                        A[mi][kc], bb, acc[mi][nt], 0, 0, 0);
            }
        }
    }

    // epilogue: D[m = quad*4 + i][n = l16] per (mi, nt) tile
    float* outb = out + (size_t)b * N_OUT_ * C_;
    #pragma unroll
    for (int mi = 0; mi < 4; ++mi) {
        #pragma unroll
        for (int nt = 0; nt < 4; ++nt) {
            float bn = bias[nt * 16 + l16];
            #pragma unroll
            for (int i = 0; i < 4; ++i) {
                int mm = mbase + mi * 16 + quad * 4 + i;
                if (mm < N_OUT_) {
                    float v = acc[mi][nt][i] + bn;
                    v = (v > 0.0f) ? v : expm1f(v);
                    outb[(size_t)mm * C_ + nt * 16 + l16] = v;
                }
            }
        }
    }
}

extern "C" void kernel_launch(void* const* d_in, const int* in_sizes, int n_in,
                              void* d_out, int out_size, void* d_ws, size_t ws_size,
                              hipStream_t stream) {
    const float* x      = (const float*)d_in[0];
    const float* tvals  = (const float*)d_in[1];
    const int*   trow   = (const int*)d_in[2];
    const int*   tcol   = (const int*)d_in[3];
    const int*   spiral = (const int*)d_in[4];
    const float* W      = (const float*)d_in[5];
    const float* bias   = (const float*)d_in[6];
    float* out = (float*)d_out;

    char* ws = (char*)d_ws;
    size_t off = 0;
    auto alloc = [&](size_t bytes) -> void* {
        void* p = ws + off;
        off += (bytes + 255) & ~(size_t)255;
        return p;
    };
    __bf16* pooled  = (__bf16*)alloc((size_t)B_ * N_OUT_ * C_ * 2);   // 51.2 MB
    __bf16* WtF     = (__bf16*)alloc(72 * 64 * 8 * 2);
    int*    cursor  = (int*)alloc(N_OUT_ * 4);
    int*    offsets = (int*)alloc((N_OUT_ + 1) * 4);
    int*    ecol    = (int*)alloc(NNZ_ * 4);
    float*  eval    = (float*)alloc(NNZ_ * 4);
    int*    counts  = (int*)alloc(N_OUT_ * 4);
    int*    bsum    = (int*)alloc(32 * 4);

    const int NBLK = (N_OUT_ + 1023) / 1024;   // 25
    hipMemsetAsync(counts, 0, N_OUT_ * 4, stream);
    hist_kernel<<<(NNZ_ + 255) / 256, 256, 0, stream>>>(trow, counts, NNZ_);
    scan1_kernel<<<NBLK, 1024, 0, stream>>>(counts, offsets, bsum, N_OUT_);
    scan2_kernel<<<1, 64, 0, stream>>>(bsum, offsets, NBLK, N_OUT_);
    scan3_kernel<<<NBLK, 1024, 0, stream>>>(offsets, bsum, cursor, N_OUT_);
    fill_kernel<<<(NNZ_ + 255) / 256, 256, 0, stream>>>(trow, tcol, tvals, cursor, ecol, eval, NNZ_);
    pool_kernel<<<8 * (N_OUT_ / 8), 256, 0, stream>>>(x, offsets, ecol, eval, pooled);
    convw_kernel<<<(72 * 64 * 8 + 255) / 256, 256, 0, stream>>>(W, WtF);
    gemm_kernel<<<8 * (2 * MT2_), 256, 0, stream>>>(pooled, spiral, WtF, bias, out);
}

// Round 6
// 285.267 us; speedup vs baseline: 1.3663x; 1.0917x over previous
//
#include <hip/hip_runtime.h>

#define B_     16
#define N_IN_  6250
#define N_OUT_ 25000
#define C_     64
#define S_     9
#define NNZ_   75000
#define MT2_   98           // ceil(N_OUT/256)

typedef __bf16 bf16x8 __attribute__((ext_vector_type(8)));
typedef float floatx4 __attribute__((ext_vector_type(4)));

__device__ inline void async_copy16(const void* g, void* l) {
    __builtin_amdgcn_global_load_lds(
        (const __attribute__((address_space(1))) void*)g,
        (__attribute__((address_space(3))) void*)l, 16, 0, 0);
}

// ---------------- CSR build ----------------

__global__ void hist_kernel(const int* __restrict__ rows, int* __restrict__ counts, int nnz) {
    int i = blockIdx.x * blockDim.x + threadIdx.x;
    if (i < nnz) atomicAdd(&counts[rows[i]], 1);
}

__global__ void scan1_kernel(const int* __restrict__ counts, int* __restrict__ offsets,
                             int* __restrict__ bsum, int n) {
    __shared__ int wsum[16];
    int t = threadIdx.x;
    int wid = t >> 6, lane = t & 63;
    int i = blockIdx.x * 1024 + t;
    int v = (i < n) ? counts[i] : 0;
    int s = v;
    #pragma unroll
    for (int d = 1; d < 64; d <<= 1) {
        int u = __shfl_up(s, d, 64);
        if (lane >= d) s += u;
    }
    if (lane == 63) wsum[wid] = s;
    __syncthreads();
    if (wid == 0 && lane < 16) {
        int ws = wsum[lane];
        #pragma unroll
        for (int d = 1; d < 16; d <<= 1) {
            int u = __shfl_up(ws, d, 64);
            if (lane >= d) ws += u;
        }
        wsum[lane] = ws;
    }
    __syncthreads();
    int wave_off = (wid == 0) ? 0 : wsum[wid - 1];
    int incl = s + wave_off;
    if (i < n) offsets[i] = incl - v;
    if (t == 1023) bsum[blockIdx.x] = incl;
}

__global__ void scan2_kernel(int* __restrict__ bsum, int* __restrict__ offsets, int nblk, int n) {
    if (threadIdx.x == 0) {
        int t = 0;
        for (int i = 0; i < nblk; ++i) { int v = bsum[i]; bsum[i] = t; t += v; }
        offsets[n] = t;
    }
}

__global__ void scan3_kernel(int* __restrict__ offsets, const int* __restrict__ bsum,
                             int* __restrict__ cursor, int n) {
    int i = blockIdx.x * 1024 + threadIdx.x;
    if (i < n) {
        int o = offsets[i] + bsum[blockIdx.x];
        offsets[i] = o;
        cursor[i] = o;
    }
}

__global__ void fill_kernel(const int* __restrict__ rows, const int* __restrict__ cols,
                            const float* __restrict__ vals, int* __restrict__ cursor,
                            int* __restrict__ ecol, float* __restrict__ eval, int nnz) {
    int i = blockIdx.x * blockDim.x + threadIdx.x;
    if (i < nnz) {
        int p = atomicAdd(&cursor[rows[i]], 1);
        ecol[p] = cols[i];
        eval[p] = vals[i];
    }
}

// ---------------- pooling (CSR gather), wave-per-row (round-2 proven) ----------------
// grid: N_OUT/4 blocks x 256 threads = 4 waves; wave w owns row blockIdx*4+w.
// Lane = (batch b = lane>>2, channel quad cq = (lane&3)*16). 16 f32 acc/lane.
// No LDS, no barriers; ecol/eval broadcast-loaded with 1-ahead prefetch.
__global__ __launch_bounds__(256) void pool_kernel(
        const float* __restrict__ x, const int* __restrict__ offsets,
        const int* __restrict__ ecol, const float* __restrict__ eval,
        __bf16* __restrict__ pooled) {
    int t = threadIdx.x;
    int wid = t >> 6, lane = t & 63;
    int row = blockIdx.x * 4 + wid;
    int b = lane >> 2;
    int cq = (lane & 3) << 4;
    int beg = offsets[row], end = offsets[row + 1];

    const float* xb = x + (size_t)b * N_IN_ * C_ + cq;
    floatx4 acc[4] = {};

    int col = 0; float v = 0.f;
    if (beg < end) { col = ecol[beg]; v = eval[beg]; }
    for (int k = beg; k < end; ++k) {
        int col2 = 0; float v2 = 0.f;
        if (k + 1 < end) { col2 = ecol[k + 1]; v2 = eval[k + 1]; }
        const floatx4* xp = reinterpret_cast<const floatx4*>(xb + (size_t)col * C_);
        #pragma unroll
        for (int j = 0; j < 4; ++j) acc[j] += xp[j] * v;
        col = col2; v = v2;
    }

    __bf16* op = pooled + ((size_t)b * N_OUT_ + row) * C_ + cq;
    bf16x8 o0, o1;
    #pragma unroll
    for (int j = 0; j < 4; ++j) {
        o0[j]     = (__bf16)acc[0][j];
        o0[j + 4] = (__bf16)acc[1][j];
        o1[j]     = (__bf16)acc[2][j];
        o1[j + 4] = (__bf16)acc[3][j];
    }
    *reinterpret_cast<bf16x8*>(op)     = o0;
    *reinterpret_cast<bf16x8*>(op + 8) = o1;
}

// ---------------- W -> WtF (bf16, MFMA-fragment-major) ----------------
// WtF[(kb*64 + n)*8 + j] = W[(kb*8 + j)*64 + n], kb = k/8 in [0,72).
__global__ void convw_kernel(const float* __restrict__ W, __bf16* __restrict__ WtF) {
    int i = blockIdx.x * blockDim.x + threadIdx.x;   // over 72*64*8
    if (i < 72 * 64 * 8) {
        int kb = i >> 9;
        int n  = (i >> 3) & 63;
        int j  = i & 7;
        WtF[i] = (__bf16)W[(kb * 8 + j) * 64 + n];
    }
}

// ---------------- spiral gather + GEMM + bias + ELU ----------------
// grid 1D = 8 * (2*MT2_), XCD-affine: bx&7 = xcd, one batch per block ->
// per-XCD pooled working set 3.2MB (L2-resident IF not evicted). Key change:
// out-writes use NONTEMPORAL stores so the 102MB f32 stream doesn't thrash
// the 4MB per-XCD L2 that serves the 460MB of A-gather traffic. A-prefetch
// depth 3 (4 rotating buffers, compile-time select) for outstanding misses.
__global__ __launch_bounds__(256, 2) void gemm_kernel(
        const __bf16* __restrict__ pooled, const int* __restrict__ spiral,
        const __bf16* __restrict__ WtF, const float* __restrict__ bias,
        float* __restrict__ out) {
    __shared__ __bf16 Bs[72 * 64 * 8];   // 73728 B -> 2 blocks/CU

    int bx = blockIdx.x;
    int xcd = bx & 7;
    int rr = bx >> 3;                    // 0..2*MT2_-1
    int half = (rr >= MT2_) ? 1 : 0;
    int mt = rr - half * MT2_;           // 0..97
    int b = xcd + 8 * half;

    int t = threadIdx.x;
    int wave = t >> 6, lane = t & 63;
    int quad = lane >> 4, l16 = lane & 15;
    int mbase = mt * 256 + wave * 64;

    // stage WtF -> Bs, lane-linear 16B chunks (4608 total, 18/thread)
    #pragma unroll
    for (int j = 0; j < 18; ++j) {
        int idx = t + j * 256;
        async_copy16((const char*)WtF + (size_t)idx * 16, (char*)Bs + idx * 16);
    }

    // per-lane spiral indices for the 4 m-subtiles, vectorized 4+4+1
    int src[4][S_];
    #pragma unroll
    for (int mi = 0; mi < 4; ++mi) {
        int m = mbase + mi * 16 + l16;
        int mc = (m < N_OUT_) ? m : 0;
        const int* sp = spiral + (size_t)mc * S_;
        int4 a0 = *reinterpret_cast<const int4*>(sp);
        int4 a1 = *reinterpret_cast<const int4*>(sp + 4);
        src[mi][0] = a0.x; src[mi][1] = a0.y; src[mi][2] = a0.z; src[mi][3] = a0.w;
        src[mi][4] = a1.x; src[mi][5] = a1.y; src[mi][6] = a1.z; src[mi][7] = a1.w;
        src[mi][8] = sp[8];
    }
    const __bf16* poolb = pooled + (size_t)b * N_OUT_ * C_;

    __syncthreads();   // staging drained (single barrier of the kernel)

    floatx4 acc[4][4] = {};
    bf16x8 A0[4][2], A1[4][2], A2[4][2], A3[4][2];

    auto loadA = [&](int s, bf16x8 (*A)[2]) {
        #pragma unroll
        for (int mi = 0; mi < 4; ++mi) {
            const __bf16* p = poolb + (size_t)src[mi][s] * C_ + quad * 8;
            A[mi][0] = *reinterpret_cast<const bf16x8*>(p);
            A[mi][1] = *reinterpret_cast<const bf16x8*>(p + 32);
        }
    };
    auto bufFor = [&](int s) -> bf16x8 (*)[2] {
        switch (s & 3) {
            case 0:  return A0;
            case 1:  return A1;
            case 2:  return A2;
            default: return A3;
        }
    };

    loadA(0, A0);
    loadA(1, A1);
    loadA(2, A2);
    #pragma unroll
    for (int s = 0; s < S_; ++s) {
        if (s + 3 < S_) {
            loadA(s + 3, bufFor(s + 3));           // depth-3 prefetch
            __builtin_amdgcn_sched_barrier(0);     // pin: loads stay ahead of MFMAs
        }
        bf16x8 (*A)[2] = bufFor(s);
        #pragma unroll
        for (int kc = 0; kc < 2; ++kc) {
            #pragma unroll
            for (int nt = 0; nt < 4; ++nt) {
                int kb = s * 8 + kc * 4 + quad;
                bf16x8 bb = *reinterpret_cast<const bf16x8*>(
                    Bs + (((kb << 6) + (nt << 4) + l16) << 3));
                #pragma unroll
                for (int mi = 0; mi < 4; ++mi)
                    acc[mi][nt] = __builtin_amdgcn_mfma_f32_16x16x32_bf16(
                        A[mi][kc], bb, acc[mi][nt], 0, 0, 0);
            }
        }
    }

    // epilogue: D[m = quad*4 + i][n = l16] per (mi, nt) tile.
    // NONTEMPORAL stores: don't let the 102MB out-stream evict pooled from L2.
    float* outb = out + (size_t)b * N_OUT_ * C_;
    #pragma unroll
    for (int mi = 0; mi < 4; ++mi) {
        #pragma unroll
        for (int nt = 0; nt < 4; ++nt) {
            float bn = bias[nt * 16 + l16];
            #pragma unroll
            for (int i = 0; i < 4; ++i) {
                int mm = mbase + mi * 16 + quad * 4 + i;
                if (mm < N_OUT_) {
                    float v = acc[mi][nt][i] + bn;
                    v = (v > 0.0f) ? v : expm1f(v);
                    __builtin_nontemporal_store(v, &outb[(size_t)mm * C_ + nt * 16 + l16]);
                }
            }
        }
    }
}

extern "C" void kernel_launch(void* const* d_in, const int* in_sizes, int n_in,
                              void* d_out, int out_size, void* d_ws, size_t ws_size,
                              hipStream_t stream) {
    const float* x      = (const float*)d_in[0];
    const float* tvals  = (const float*)d_in[1];
    const int*   trow   = (const int*)d_in[2];
    const int*   tcol   = (const int*)d_in[3];
    const int*   spiral = (const int*)d_in[4];
    const float* W      = (const float*)d_in[5];
    const float* bias   = (const float*)d_in[6];
    float* out = (float*)d_out;

    char* ws = (char*)d_ws;
    size_t off = 0;
    auto alloc = [&](size_t bytes) -> void* {
        void* p = ws + off;
        off += (bytes + 255) & ~(size_t)255;
        return p;
    };
    __bf16* pooled  = (__bf16*)alloc((size_t)B_ * N_OUT_ * C_ * 2);   // 51.2 MB
    __bf16* WtF     = (__bf16*)alloc(72 * 64 * 8 * 2);
    int*    cursor  = (int*)alloc(N_OUT_ * 4);
    int*    offsets = (int*)alloc((N_OUT_ + 1) * 4);
    int*    ecol    = (int*)alloc(NNZ_ * 4);
    float*  eval    = (float*)alloc(NNZ_ * 4);
    int*    counts  = (int*)alloc(N_OUT_ * 4);
    int*    bsum    = (int*)alloc(32 * 4);

    const int NBLK = (N_OUT_ + 1023) / 1024;   // 25
    hipMemsetAsync(counts, 0, N_OUT_ * 4, stream);
    hist_kernel<<<(NNZ_ + 255) / 256, 256, 0, stream>>>(trow, counts, NNZ_);
    scan1_kernel<<<NBLK, 1024, 0, stream>>>(counts, offsets, bsum, N_OUT_);
    scan2_kernel<<<1, 64, 0, stream>>>(bsum, offsets, NBLK, N_OUT_);
    scan3_kernel<<<NBLK, 1024, 0, stream>>>(offsets, bsum, cursor, N_OUT_);
    fill_kernel<<<(NNZ_ + 255) / 256, 256, 0, stream>>>(trow, tcol, tvals, cursor, ecol, eval, NNZ_);
    pool_kernel<<<N_OUT_ / 4, 256, 0, stream>>>(x, offsets, ecol, eval, pooled);
    convw_kernel<<<(72 * 64 * 8 + 255) / 256, 256, 0, stream>>>(W, WtF);
    gemm_kernel<<<8 * (2 * MT2_), 256, 0, stream>>>(pooled, spiral, WtF, bias, out);
}